// Round 1
// baseline (633.529 us; speedup 1.0000x reference)
//
#include <hip/hip_runtime.h>
#include <math.h>

#define SCALE_F   64.0f
#define MARGIN_F  0.4f
#define H_F       0.333f
#define EPS_F     1e-3f

// ---------------------------------------------------------------------------
// Kernel 1: out = logits * SCALE, fully vectorized float4 copy-scale.
// B*C = 102,400,000 is divisible by 4 -> exact float4 coverage, no tail.
// ---------------------------------------------------------------------------
__global__ __launch_bounds__(256) void adaface_scale_kernel(
    const float4* __restrict__ in, float4* __restrict__ out, int n4) {
    int idx = blockIdx.x * blockDim.x + threadIdx.x;
    if (idx < n4) {
        float4 v = in[idx];
        v.x *= SCALE_F; v.y *= SCALE_F; v.z *= SCALE_F; v.w *= SCALE_F;
        out[idx] = v;
    }
}

// ---------------------------------------------------------------------------
// Kernel 2: one block, B threads (B=1024). Each thread owns one row.
//  - clip norms -> safe_norms
//  - block reduction for mean / unbiased std (ddof=1)
//  - margin_scaler, g_angular, g_add
//  - gather original target logit, apply angular+additive margin
//  - overwrite out[row*C + label] with new_target * SCALE
// Runs after kernel 1 on the same stream, so this write is final.
// ---------------------------------------------------------------------------
__global__ __launch_bounds__(1024) void adaface_fixup_kernel(
    const float* __restrict__ logits,
    const float* __restrict__ norms,
    const int*   __restrict__ labels,
    float* __restrict__ out, int B, int C) {

    int row = threadIdx.x;
    bool active = (row < B);

    float sn = 0.0f;
    if (active) {
        sn = norms[row];
        sn = fminf(fmaxf(sn, 1e-3f), 100.0f);
    }

    // wave (64-lane) shuffle reduction of sum and sum-of-squares
    float v  = sn;
    float v2 = sn * sn;
    #pragma unroll
    for (int off = 32; off > 0; off >>= 1) {
        v  += __shfl_down(v,  off, 64);
        v2 += __shfl_down(v2, off, 64);
    }

    __shared__ float s_sum[16];   // up to 1024/64 waves
    __shared__ float s_sq[16];
    __shared__ float s_mean, s_std;

    int wave = threadIdx.x >> 6;
    int lane = threadIdx.x & 63;
    if (lane == 0) { s_sum[wave] = v; s_sq[wave] = v2; }
    __syncthreads();

    if (threadIdx.x == 0) {
        int nwaves = (blockDim.x + 63) >> 6;
        float tsum = 0.0f, tsq = 0.0f;
        for (int i = 0; i < nwaves; ++i) { tsum += s_sum[i]; tsq += s_sq[i]; }
        float mean = tsum / (float)B;
        float var  = (tsq - tsum * tsum / (float)B) / (float)(B - 1);
        s_mean = mean;
        s_std  = sqrtf(fmaxf(var, 0.0f));
    }
    __syncthreads();

    if (!active) return;

    float mean = s_mean;
    float stdv = s_std;

    float ms = (sn - mean) / (stdv + EPS_F) * H_F;
    ms = fminf(fmaxf(ms, -1.0f), 1.0f);

    float g_ang = -MARGIN_F * ms;
    float g_add =  MARGIN_F + MARGIN_F * ms;

    int lab = labels[row];
    long long pos = (long long)row * (long long)C + (long long)lab;
    float tl = logits[pos];

    float theta = acosf(tl) + g_ang;
    theta = fminf(fmaxf(theta, EPS_F), (float)M_PI - EPS_F);
    float nt = __cosf(theta) - g_add;   // fast cos is well within tolerance
    // use precise cosf to be safe:
    nt = cosf(theta) - g_add;

    out[pos] = nt * SCALE_F;
}

extern "C" void kernel_launch(void* const* d_in, const int* in_sizes, int n_in,
                              void* d_out, int out_size, void* d_ws, size_t ws_size,
                              hipStream_t stream) {
    const float* logits = (const float*)d_in[0];
    const float* norms  = (const float*)d_in[1];
    const int*   labels = (const int*)d_in[2];
    float* out = (float*)d_out;

    int B = in_sizes[1];              // norms is [B,1]
    int C = in_sizes[0] / B;          // logits is [B,C]
    int n  = in_sizes[0];
    int n4 = n >> 2;                  // exact: B*C % 4 == 0

    int threads = 256;
    int blocks  = (n4 + threads - 1) / threads;
    adaface_scale_kernel<<<blocks, threads, 0, stream>>>(
        (const float4*)logits, (float4*)out, n4);

    adaface_fixup_kernel<<<1, 1024, 0, stream>>>(logits, norms, labels, out, B, C);
}